// Round 2
// baseline (337.916 us; speedup 1.0000x reference)
//
#include <hip/hip_runtime.h>

// Problem shape (fixed by setup_inputs): inputs [B=32, T=4096, F=256] fp32.
constexpr int B_ = 32;
constexpr int T_ = 4096;
constexpr int F_ = 256;
constexpr int CHUNKS = 64;          // chunks along T
constexpr int L_ = T_ / CHUNKS;     // 64 steps per chunk
constexpr float EPS_ = 1e-6f;

// ---- ordered-uint encoding for float atomic min/max (handles any sign) ----
__device__ __forceinline__ unsigned f2ord(float f) {
    unsigned u = __float_as_uint(f);
    return (u & 0x80000000u) ? ~u : (u | 0x80000000u);
}
__device__ __forceinline__ float ord2f(unsigned u) {
    return (u & 0x80000000u) ? __uint_as_float(u ^ 0x80000000u)
                             : __uint_as_float(~u);
}

__device__ __forceinline__ float clamp01(float v) {
    return fminf(fmaxf(v, 0.0f), 1.0f);
}

// ---------------------------------------------------------------------------
// Kernel A: chunk-local EMA with zero seed; emit end-state E[b][c][f].
// One wave per (b,c); lane handles 4 consecutive f via float4.
// ---------------------------------------------------------------------------
__global__ __launch_bounds__(64) void ema_chunk_local(
        const float* __restrict__ x, const float* __restrict__ smooth,
        float* __restrict__ E) {
    const int bc = blockIdx.x;        // b*CHUNKS + c  (contiguous in memory)
    const int lane = threadIdx.x;     // 0..63 -> f4 group
    const float w = clamp01(smooth[0]);
    const float d = 1.0f - w;

    const float4* xp = reinterpret_cast<const float4*>(
                           x + (size_t)bc * L_ * F_) + lane;
    float4 a = make_float4(0.f, 0.f, 0.f, 0.f);

    for (int t0 = 0; t0 < L_; t0 += 8) {
        float4 v[8];
#pragma unroll
        for (int i = 0; i < 8; ++i) v[i] = xp[(size_t)(t0 + i) * (F_ / 4)];
#pragma unroll
        for (int i = 0; i < 8; ++i) {
            a.x = fmaf(w, v[i].x, d * a.x);
            a.y = fmaf(w, v[i].y, d * a.y);
            a.z = fmaf(w, v[i].z, d * a.z);
            a.w = fmaf(w, v[i].w, d * a.w);
        }
    }
    reinterpret_cast<float4*>(E + (size_t)bc * F_)[lane] = a;
}

// ---------------------------------------------------------------------------
// Kernel B: cross-chunk carry scan. In_0 = x[b,0,f] (reference initial state);
// In_c = d^L * In_{c-1} + E_{c-1}. Also initializes the min/max atomic slots.
// One wave per b; lane handles 4 f via float4.
// ---------------------------------------------------------------------------
__global__ __launch_bounds__(64) void ema_carry(
        const float* __restrict__ x, const float* __restrict__ smooth,
        const float* __restrict__ E, float* __restrict__ In,
        unsigned* __restrict__ mm) {
    const int b = blockIdx.x;
    const int lane = threadIdx.x;
    if (b == 0 && lane == 0) {
        mm[0] = 0xFFFFFFFFu;  // ordered-min init (= +inf)
        mm[1] = 0x00000000u;  // ordered-max init (= -inf)
    }
    const float w = clamp01(smooth[0]);
    const float d = 1.0f - w;
    // dL = d^64 via repeated squaring (6 muls) — avoids libm powf
    float dL = d;
    dL *= dL;  // d^2
    dL *= dL;  // d^4
    dL *= dL;  // d^8
    dL *= dL;  // d^16
    dL *= dL;  // d^32
    dL *= dL;  // d^64

    float4 cur = reinterpret_cast<const float4*>(
                     x + (size_t)b * T_ * F_)[lane];
    for (int c = 0; c < CHUNKS; ++c) {
        const size_t idx = ((size_t)b * CHUNKS + c) * (F_ / 4) + lane;
        reinterpret_cast<float4*>(In)[idx] = cur;
        const float4 e = reinterpret_cast<const float4*>(E)[idx];
        cur.x = fmaf(dL, cur.x, e.x);
        cur.y = fmaf(dL, cur.y, e.y);
        cur.z = fmaf(dL, cur.z, e.z);
        cur.w = fmaf(dL, cur.w, e.w);
    }
}

// ---------------------------------------------------------------------------
// Kernel C: seeded re-scan + PCEN compression + global min/max reduction.
// out_pre = (x*(EPS+ema)^-g + bias)^(1/r) - bias^(1/r)
// ---------------------------------------------------------------------------
__device__ __forceinline__ float pcen_elem(float xv, float av, float g,
                                           float inv_r, float bias,
                                           float bpow) {
    // (eps+a)^-g  via exp2/log2 (v_exp_f32 / v_log_f32)
    const float p = __builtin_exp2f(-g * __builtin_log2f(EPS_ + av));
    const float base = fmaf(xv, p, bias);              // >= bias > 0
    return __builtin_exp2f(inv_r * __builtin_log2f(base)) - bpow;
}

__global__ __launch_bounds__(64) void pcen_out(
        const float* __restrict__ x, const float* __restrict__ In,
        const float* __restrict__ gain, const float* __restrict__ bias_p,
        const float* __restrict__ root, const float* __restrict__ smooth,
        float* __restrict__ out, unsigned* __restrict__ mm) {
    const int bc = blockIdx.x;
    const int lane = threadIdx.x;
    const float w = clamp01(smooth[0]);
    const float d = 1.0f - w;
    const float g = fminf(gain[0], 1.0f);
    const float r = fmaxf(root[0], 1.0f);
    const float inv_r = 1.0f / r;
    const float bias = bias_p[0];
    const float bpow = __builtin_exp2f(inv_r * __builtin_log2f(bias));

    const float4* xp = reinterpret_cast<const float4*>(
                           x + (size_t)bc * L_ * F_) + lane;
    float4* op = reinterpret_cast<float4*>(
                     out + (size_t)bc * L_ * F_) + lane;
    float4 a = reinterpret_cast<const float4*>(In)[(size_t)bc * (F_ / 4) + lane];

    float lmin = __builtin_inff(), lmax = -__builtin_inff();
    for (int t0 = 0; t0 < L_; t0 += 8) {
        float4 v[8];
#pragma unroll
        for (int i = 0; i < 8; ++i) v[i] = xp[(size_t)(t0 + i) * (F_ / 4)];
#pragma unroll
        for (int i = 0; i < 8; ++i) {
            a.x = fmaf(w, v[i].x, d * a.x);
            a.y = fmaf(w, v[i].y, d * a.y);
            a.z = fmaf(w, v[i].z, d * a.z);
            a.w = fmaf(w, v[i].w, d * a.w);
            float4 o;
            o.x = pcen_elem(v[i].x, a.x, g, inv_r, bias, bpow);
            o.y = pcen_elem(v[i].y, a.y, g, inv_r, bias, bpow);
            o.z = pcen_elem(v[i].z, a.z, g, inv_r, bias, bpow);
            o.w = pcen_elem(v[i].w, a.w, g, inv_r, bias, bpow);
            lmin = fminf(lmin, fminf(fminf(o.x, o.y), fminf(o.z, o.w)));
            lmax = fmaxf(lmax, fmaxf(fmaxf(o.x, o.y), fmaxf(o.z, o.w)));
            op[(size_t)(t0 + i) * (F_ / 4)] = o;
        }
    }
    // wave-level (64-lane) butterfly reduction, then one atomic pair per block
#pragma unroll
    for (int off = 32; off > 0; off >>= 1) {
        lmin = fminf(lmin, __shfl_xor(lmin, off));
        lmax = fmaxf(lmax, __shfl_xor(lmax, off));
    }
    if (lane == 0) {
        atomicMin(&mm[0], f2ord(lmin));
        atomicMax(&mm[1], f2ord(lmax));
    }
}

// ---------------------------------------------------------------------------
// Kernel D: in-place global min/max normalization: out = out*s + o
// ---------------------------------------------------------------------------
__global__ __launch_bounds__(256) void norm_apply(
        float* __restrict__ out, const unsigned* __restrict__ mm, int n4) {
    const float mn = ord2f(mm[0]);
    const float mx = ord2f(mm[1]);
    const float s = 2.0f / (mx - mn);
    const float o = fmaf(-mn, s, -1.0f);
    float4* p = reinterpret_cast<float4*>(out);
    const int stride = gridDim.x * blockDim.x;
    for (int i = blockIdx.x * blockDim.x + threadIdx.x; i < n4; i += stride) {
        float4 v = p[i];
        v.x = fmaf(v.x, s, o);
        v.y = fmaf(v.y, s, o);
        v.z = fmaf(v.z, s, o);
        v.w = fmaf(v.w, s, o);
        p[i] = v;
    }
}

extern "C" void kernel_launch(void* const* d_in, const int* in_sizes, int n_in,
                              void* d_out, int out_size, void* d_ws, size_t ws_size,
                              hipStream_t stream) {
    const float* x      = (const float*)d_in[0];
    const float* gain   = (const float*)d_in[1];
    const float* bias   = (const float*)d_in[2];
    const float* root   = (const float*)d_in[3];
    const float* smooth = (const float*)d_in[4];
    float* out = (float*)d_out;

    // ws layout: E [B*CHUNKS*F] | In [B*CHUNKS*F] | mm[2]  (~4 MiB + 8 B)
    float* E  = (float*)d_ws;
    float* In = E + (size_t)B_ * CHUNKS * F_;
    unsigned* mm = (unsigned*)(In + (size_t)B_ * CHUNKS * F_);

    ema_chunk_local<<<B_ * CHUNKS, 64, 0, stream>>>(x, smooth, E);
    ema_carry<<<B_, 64, 0, stream>>>(x, smooth, E, In, mm);
    pcen_out<<<B_ * CHUNKS, 64, 0, stream>>>(x, In, gain, bias, root, smooth,
                                             out, mm);
    norm_apply<<<2048, 256, 0, stream>>>(out, mm, (B_ * T_ * F_) / 4);
}